// Round 1
// baseline (1348.297 us; speedup 1.0000x reference)
//
#include <hip/hip_runtime.h>
#include <math.h>

typedef __bf16 bf16;
typedef __attribute__((ext_vector_type(8))) __bf16 bf16x8;
typedef __attribute__((ext_vector_type(4))) float f32x4;

#define T_HASH (1u << 19)
#define PRIME1 2654435761u
#define PRIME2 805459861u

struct Levels { int R[16]; int dense[16]; };

__device__ __forceinline__ unsigned umin_(unsigned a, unsigned b) { return a < b ? a : b; }

// swizzled LDS byte offset: rows are 512B (256 bf16), XOR row-bits into the 16B-slot bits
__device__ __forceinline__ int swzoff(int row, int colByte) {
    return row * 512 + (colByte ^ ((row & 7) << 4));
}

__device__ __forceinline__ void stb(char* base, int row, int col, float v) {
    *(bf16*)(base + swzoff(row, col * 2)) = (bf16)v;
}

// ---------------- weight prep: W = g * v / ||v||_row, cast to bf16, pad ----------------
__global__ void prep_weights(const float* __restrict__ v0, const float* __restrict__ g0,
                             const float* __restrict__ v1, const float* __restrict__ g1,
                             const float* __restrict__ v2, const float* __restrict__ g2,
                             unsigned short* __restrict__ W0, unsigned short* __restrict__ W1,
                             unsigned short* __restrict__ W2) {
    int r = blockIdx.x;
    int lane = threadIdx.x;
    const float* src = nullptr; const float* g = nullptr; unsigned short* dst; int K, Kp, row;
    if (r < 256)      { row = r;       src = v0 + row * 71;  g = g0; dst = W0 + row * 96;  K = 71;  Kp = 96;  }
    else if (r < 512) { row = r - 256; src = v1 + row * 256; g = g1; dst = W1 + row * 256; K = 256; Kp = 256; }
    else              { row = r - 512; if (row < 257) { src = v2 + row * 256; g = g2; }
                        dst = W2 + row * 256; K = 256; Kp = 256; }
    float ss = 0.f;
    if (src) for (int c = lane; c < K; c += 64) { float v = src[c]; ss += v * v; }
    for (int off = 32; off; off >>= 1) ss += __shfl_down(ss, off);
    ss = __shfl(ss, 0);
    float scale = src ? (g[row] / sqrtf(ss)) : 0.f;
    for (int c = lane; c < Kp; c += 64) {
        float v = (src && c < K) ? src[c] * scale : 0.f;
        bf16 h = (bf16)v;
        dst[c] = *(unsigned short*)&h;
    }
}

// ---------------- fused: encode -> L1 -> L2 -> L3 ----------------
// block = 64 points, 512 threads (8 waves). waves: wm = wave>>2 (2), wn = wave&3 (4)
// layers 1-2: m_rep=2 (32 rows/wave), n_rep=4 (tiles nt = wn + 4*nr)

__device__ __forceinline__ void layer_lds(const char* __restrict__ inbuf,
                                          const unsigned short* __restrict__ W, const int rowlen,
                                          const float* __restrict__ bias,
                                          char* __restrict__ outbuf, int tid, int ksteps) {
    const int lane = tid & 63, wave = tid >> 6;
    const int wm = wave >> 2, wn = wave & 3;
    const int lrow = lane & 15, lk = lane >> 4;
    f32x4 acc[2][4] = {};
    for (int ks = 0; ks < ksteps; ++ks) {
        const int k0 = ks * 32 + lk * 8;
        bf16x8 a[2], b[4];
#pragma unroll
        for (int mr = 0; mr < 2; ++mr) {
            int row = wm * 32 + mr * 16 + lrow;
            a[mr] = *(const bf16x8*)(inbuf + swzoff(row, k0 * 2));
        }
#pragma unroll
        for (int nr = 0; nr < 4; ++nr) {
            int wrow = (wn + 4 * nr) * 16 + lrow;
            b[nr] = *(const bf16x8*)(W + wrow * rowlen + k0);
        }
#pragma unroll
        for (int mr = 0; mr < 2; ++mr)
#pragma unroll
            for (int nr = 0; nr < 4; ++nr)
                acc[mr][nr] = __builtin_amdgcn_mfma_f32_16x16x32_bf16(a[mr], b[nr], acc[mr][nr], 0, 0, 0);
    }
#pragma unroll
    for (int mr = 0; mr < 2; ++mr)
#pragma unroll
        for (int nr = 0; nr < 4; ++nr) {
            int col = (wn + 4 * nr) * 16 + lrow;
            float bv = bias[col];
#pragma unroll
            for (int j = 0; j < 4; ++j) {
                int row = wm * 32 + mr * 16 + lk * 4 + j;
                float v = acc[mr][nr][j] + bv;
                float z = 100.f * v;
                float y = (z > 15.f) ? v : (log1pf(expf(z)) * 0.01f);  // softplus(100v)/100
                stb(outbuf, row, col, y);
            }
        }
}

__device__ __forceinline__ void layer_out(const char* __restrict__ inbuf,
                                          const unsigned short* __restrict__ W2,
                                          const float* __restrict__ b2,
                                          float* __restrict__ out, int tid, int blk) {
    const int lane = tid & 63, wave = tid >> 6;
    const int wm = wave >> 2, wn = wave & 3;
    const int lrow = lane & 15, lk = lane >> 4;
    f32x4 acc[2][5] = {};
    for (int ks = 0; ks < 8; ++ks) {
        const int k0 = ks * 32 + lk * 8;
        bf16x8 a[2];
#pragma unroll
        for (int mr = 0; mr < 2; ++mr) {
            int row = wm * 32 + mr * 16 + lrow;
            a[mr] = *(const bf16x8*)(inbuf + swzoff(row, k0 * 2));
        }
#pragma unroll
        for (int nr = 0; nr < 5; ++nr) {
            int nt = wn + 4 * nr;
            if (nt >= 17) continue;
            bf16x8 b = *(const bf16x8*)(W2 + (nt * 16 + lrow) * 256 + k0);
#pragma unroll
            for (int mr = 0; mr < 2; ++mr)
                acc[mr][nr] = __builtin_amdgcn_mfma_f32_16x16x32_bf16(a[mr], b, acc[mr][nr], 0, 0, 0);
        }
    }
#pragma unroll
    for (int nr = 0; nr < 5; ++nr) {
        int nt = wn + 4 * nr;
        if (nt >= 17) continue;
        int col = nt * 16 + lrow;
        if (col >= 257) continue;
        float bv = b2[col];
#pragma unroll
        for (int mr = 0; mr < 2; ++mr)
#pragma unroll
            for (int j = 0; j < 4; ++j) {
                int row = wm * 32 + mr * 16 + lk * 4 + j;
                out[(size_t)(blk * 64 + row) * 257 + col] = acc[mr][nr][j] + bv;
            }
    }
}

__global__ __launch_bounds__(512, 4)
void fused_net(const float* __restrict__ x, const float2* __restrict__ tables,
               const unsigned short* __restrict__ W0, const unsigned short* __restrict__ W1,
               const unsigned short* __restrict__ W2,
               const float* __restrict__ b0, const float* __restrict__ b1, const float* __restrict__ b2,
               float* __restrict__ out, Levels lv) {
    __shared__ __align__(16) char smem[65536 + 64 * 3 * 4];
    float* xls = (float*)(smem + 65536);
    char* buf0 = smem;            // h0, later h2
    char* buf1 = smem + 32768;    // h1
    const int tid = threadIdx.x;
    const int blk = blockIdx.x;

    for (int i = tid; i < 64 * 3; i += 512) xls[i] = x[(size_t)blk * 64 * 3 + i];
    __syncthreads();

    const int p = tid >> 3, sub = tid & 7;
    const float xr0 = xls[p * 3 + 0], xr1 = xls[p * 3 + 1], xr2 = xls[p * 3 + 2];

    if (sub < 4) {
        // 4 hash levels per thread
        const float cx = fminf(fmaxf(xr0, 0.f), 1.f);
        const float cy = fminf(fmaxf(xr1, 0.f), 1.f);
        const float cz = fminf(fmaxf(xr2, 0.f), 1.f);
        for (int t = 0; t < 4; ++t) {
            const int l = sub * 4 + t;
            const int R = lv.R[l];
            const float Rf = (float)R;
            float px = cx * Rf, py = cy * Rf, pz = cz * Rf;
            float fx = floorf(px), fy = floorf(py), fz = floorf(pz);
            float wx = px - fx, wy = py - fy, wz = pz - fz;
            unsigned ix = (unsigned)fx, iy = (unsigned)fy, iz = (unsigned)fz;
            const unsigned Ru = (unsigned)R;
            const unsigned s1 = Ru + 1u, s2 = s1 * s1;
            const bool dense = lv.dense[l] != 0;
            const float2* tbl = tables + (size_t)l * T_HASH;
            float a0 = 0.f, a1 = 0.f;
#pragma unroll
            for (int c = 0; c < 8; ++c) {
                unsigned ox = c & 1u, oy = (c >> 1) & 1u, oz = (c >> 2) & 1u;
                unsigned i0 = umin_(ix + ox, Ru), i1 = umin_(iy + oy, Ru), i2 = umin_(iz + oz, Ru);
                unsigned flat = dense ? (i0 + s1 * i1 + s2 * i2)
                                      : ((i0 ^ (i1 * PRIME1) ^ (i2 * PRIME2)) & (T_HASH - 1u));
                float2 e = tbl[flat];
                float wc = (ox ? wx : 1.f - wx) * (oy ? wy : 1.f - wy) * (oz ? wz : 1.f - wz);
                a0 += wc * e.x; a1 += wc * e.y;
            }
            stb(buf0, p, 39 + 2 * l, a0);
            stb(buf0, p, 40 + 2 * l, a1);
        }
    } else if (sub == 4) {
        stb(buf0, p, 0, xr0); stb(buf0, p, 1, xr1); stb(buf0, p, 2, xr2);
        stb(buf0, p, 3, sinf(xr0)); stb(buf0, p, 4, sinf(xr1)); stb(buf0, p, 5, sinf(xr2));
        stb(buf0, p, 6, cosf(xr0)); stb(buf0, p, 7, cosf(xr1)); stb(buf0, p, 8, cosf(xr2));
    } else if (sub == 5) {
        for (int j = 1; j <= 2; ++j) {
            float f = (float)(1 << j); int c = 3 + 6 * j;
            stb(buf0, p, c + 0, sinf(f * xr0)); stb(buf0, p, c + 1, sinf(f * xr1)); stb(buf0, p, c + 2, sinf(f * xr2));
            stb(buf0, p, c + 3, cosf(f * xr0)); stb(buf0, p, c + 4, cosf(f * xr1)); stb(buf0, p, c + 5, cosf(f * xr2));
        }
    } else if (sub == 6) {
        for (int j = 3; j <= 4; ++j) {
            float f = (float)(1 << j); int c = 3 + 6 * j;
            stb(buf0, p, c + 0, sinf(f * xr0)); stb(buf0, p, c + 1, sinf(f * xr1)); stb(buf0, p, c + 2, sinf(f * xr2));
            stb(buf0, p, c + 3, cosf(f * xr0)); stb(buf0, p, c + 4, cosf(f * xr1)); stb(buf0, p, c + 5, cosf(f * xr2));
        }
    } else { // sub == 7
        { float f = 32.f; int c = 33;
          stb(buf0, p, c + 0, sinf(f * xr0)); stb(buf0, p, c + 1, sinf(f * xr1)); stb(buf0, p, c + 2, sinf(f * xr2));
          stb(buf0, p, c + 3, cosf(f * xr0)); stb(buf0, p, c + 4, cosf(f * xr1)); stb(buf0, p, c + 5, cosf(f * xr2)); }
        for (int c = 71; c < 96; ++c) stb(buf0, p, c, 0.f);
    }
    __syncthreads();

    layer_lds(buf0, W0, 96, b0, buf1, tid, 3);   // 71(->96) -> 256
    __syncthreads();
    layer_lds(buf1, W1, 256, b1, buf0, tid, 8);  // 256 -> 256
    __syncthreads();
    layer_out(buf0, W2, b2, out, tid, blk);      // 256 -> 257 (padded 272)
}

extern "C" void kernel_launch(void* const* d_in, const int* in_sizes, int n_in,
                              void* d_out, int out_size, void* d_ws, size_t ws_size,
                              hipStream_t stream) {
    const float*  x      = (const float*)d_in[0];
    const float2* tables = (const float2*)d_in[1];
    const float*  v0 = (const float*)d_in[2];
    const float*  g0 = (const float*)d_in[3];
    const float*  b0 = (const float*)d_in[4];
    const float*  v1 = (const float*)d_in[5];
    const float*  g1 = (const float*)d_in[6];
    const float*  b1 = (const float*)d_in[7];
    const float*  v2 = (const float*)d_in[8];
    const float*  g2 = (const float*)d_in[9];
    const float*  b2 = (const float*)d_in[10];

    unsigned short* W0 = (unsigned short*)d_ws;          // [256][96]
    unsigned short* W1 = W0 + 256 * 96;                  // [256][256]
    unsigned short* W2 = W1 + 256 * 256;                 // [272][256]

    Levels lv;
    double SCALE = pow(2.0, log2(2048.0 / 16.0) / 15.0);
    for (int l = 0; l < 16; ++l) {
        double r = 16.0 * pow(SCALE, (double)l);
        int R = (int)ceil(r);
        lv.R[l] = R;
        long long s = (long long)R + 1;
        lv.dense[l] = (s * s * s <= (long long)T_HASH) ? 1 : 0;
    }

    prep_weights<<<784, 64, 0, stream>>>(v0, g0, v1, g1, v2, g2, W0, W1, W2);

    int n = in_sizes[0] / 3;          // 524288
    int nblk = n / 64;                // 8192
    fused_net<<<nblk, 512, 0, stream>>>(x, tables, W0, W1, W2, b0, b1, b2, (float*)d_out, lv);
}

// Round 2
// 972.195 us; speedup vs baseline: 1.3869x; 1.3869x over previous
//
#include <hip/hip_runtime.h>
#include <math.h>

typedef __bf16 bf16;
typedef __attribute__((ext_vector_type(8))) __bf16 bf16x8;
typedef __attribute__((ext_vector_type(4))) float f32x4;

#define T_HASH (1u << 19)
#define PRIME1 2654435761u
#define PRIME2 805459861u

struct Levels { unsigned R[16]; unsigned mY[16]; unsigned mZ[16]; unsigned df[16]; };

__device__ __forceinline__ unsigned umin_(unsigned a, unsigned b) { return a < b ? a : b; }

// swizzled LDS byte offset: rows are 512B (256 bf16), XOR row-bits into the 16B-slot bits
__device__ __forceinline__ int swzoff(int row, int colByte) {
    return row * 512 + (colByte ^ ((row & 7) << 4));
}

__device__ __forceinline__ void stb(char* base, int row, int col, float v) {
    *(bf16*)(base + swzoff(row, col * 2)) = (bf16)v;
}

// fast softplus(100v)/100: exact to ~1e-7 abs; v>0.25 -> identity (tail < 2e-13)
__device__ __forceinline__ float softplus100f(float v) {
    float u = v * 144.2695041f;                       // 100 * log2(e)
    float e = __builtin_amdgcn_exp2f(u);
    float y = __builtin_amdgcn_logf(1.f + e) * 0.006931471806f;  // log2->ln, /100
    return v > 0.25f ? v : y;
}

// ---------------- weight prep: W = g * v / ||v||_row, cast to bf16, pad ----------------
__global__ void prep_weights(const float* __restrict__ v0, const float* __restrict__ g0,
                             const float* __restrict__ v1, const float* __restrict__ g1,
                             const float* __restrict__ v2, const float* __restrict__ g2,
                             unsigned short* __restrict__ W0, unsigned short* __restrict__ W1,
                             unsigned short* __restrict__ W2) {
    int r = blockIdx.x;
    int lane = threadIdx.x;
    const float* src = nullptr; const float* g = nullptr; unsigned short* dst; int K, Kp, row;
    if (r < 256)      { row = r;       src = v0 + row * 71;  g = g0; dst = W0 + row * 96;  K = 71;  Kp = 96;  }
    else if (r < 512) { row = r - 256; src = v1 + row * 256; g = g1; dst = W1 + row * 256; K = 256; Kp = 256; }
    else              { row = r - 512; if (row < 257) { src = v2 + row * 256; g = g2; }
                        dst = W2 + row * 256; K = 256; Kp = 256; }
    float ss = 0.f;
    if (src) for (int c = lane; c < K; c += 64) { float v = src[c]; ss += v * v; }
    for (int off = 32; off; off >>= 1) ss += __shfl_down(ss, off);
    ss = __shfl(ss, 0);
    float scale = src ? (g[row] / sqrtf(ss)) : 0.f;
    for (int c = lane; c < Kp; c += 64) {
        float v = (src && c < K) ? src[c] * scale : 0.f;
        bf16 h = (bf16)v;
        dst[c] = *(unsigned short*)&h;
    }
}

// ---------------- fused: encode -> L1 -> L2 -> L3 ----------------
// block = 64 points, 512 threads (8 waves). waves: wm = wave>>2 (2), wn = wave&3 (4)

__device__ __forceinline__ void layer_lds(const char* __restrict__ inbuf,
                                          const unsigned short* __restrict__ W, const int rowlen,
                                          const float* __restrict__ bias,
                                          char* __restrict__ outbuf, int tid, int ksteps) {
    const int lane = tid & 63, wave = tid >> 6;
    const int wm = wave >> 2, wn = wave & 3;
    const int lrow = lane & 15, lk = lane >> 4;
    f32x4 acc[2][4] = {};
    for (int ks = 0; ks < ksteps; ++ks) {
        const int k0 = ks * 32 + lk * 8;
        bf16x8 a[2], b[4];
#pragma unroll
        for (int mr = 0; mr < 2; ++mr) {
            int row = wm * 32 + mr * 16 + lrow;
            a[mr] = *(const bf16x8*)(inbuf + swzoff(row, k0 * 2));
        }
#pragma unroll
        for (int nr = 0; nr < 4; ++nr) {
            int wrow = (wn + 4 * nr) * 16 + lrow;
            b[nr] = *(const bf16x8*)(W + wrow * rowlen + k0);
        }
#pragma unroll
        for (int mr = 0; mr < 2; ++mr)
#pragma unroll
            for (int nr = 0; nr < 4; ++nr)
                acc[mr][nr] = __builtin_amdgcn_mfma_f32_16x16x32_bf16(a[mr], b[nr], acc[mr][nr], 0, 0, 0);
    }
#pragma unroll
    for (int mr = 0; mr < 2; ++mr)
#pragma unroll
        for (int nr = 0; nr < 4; ++nr) {
            int col = (wn + 4 * nr) * 16 + lrow;
            float bv = bias[col];
#pragma unroll
            for (int j = 0; j < 4; ++j) {
                int row = wm * 32 + mr * 16 + lk * 4 + j;
                stb(outbuf, row, col, softplus100f(acc[mr][nr][j] + bv));
            }
        }
}

__device__ __forceinline__ void layer_out(const char* __restrict__ inbuf,
                                          const unsigned short* __restrict__ W2,
                                          const float* __restrict__ b2,
                                          float* __restrict__ out, int tid, int blk) {
    const int lane = tid & 63, wave = tid >> 6;
    const int wm = wave >> 2, wn = wave & 3;
    const int lrow = lane & 15, lk = lane >> 4;
    f32x4 acc[2][5] = {};
    for (int ks = 0; ks < 8; ++ks) {
        const int k0 = ks * 32 + lk * 8;
        bf16x8 a[2];
#pragma unroll
        for (int mr = 0; mr < 2; ++mr) {
            int row = wm * 32 + mr * 16 + lrow;
            a[mr] = *(const bf16x8*)(inbuf + swzoff(row, k0 * 2));
        }
#pragma unroll
        for (int nr = 0; nr < 5; ++nr) {
            int nt = wn + 4 * nr;
            if (nt >= 17) continue;
            bf16x8 b = *(const bf16x8*)(W2 + (nt * 16 + lrow) * 256 + k0);
#pragma unroll
            for (int mr = 0; mr < 2; ++mr)
                acc[mr][nr] = __builtin_amdgcn_mfma_f32_16x16x32_bf16(a[mr], b, acc[mr][nr], 0, 0, 0);
        }
    }
#pragma unroll
    for (int nr = 0; nr < 5; ++nr) {
        int nt = wn + 4 * nr;
        if (nt >= 17) continue;
        int col = nt * 16 + lrow;
        if (col >= 257) continue;
        float bv = b2[col];
#pragma unroll
        for (int mr = 0; mr < 2; ++mr)
#pragma unroll
            for (int j = 0; j < 4; ++j) {
                int row = wm * 32 + mr * 16 + lk * 4 + j;
                out[(size_t)(blk * 64 + row) * 257 + col] = acc[mr][nr][j] + bv;
            }
    }
}

__global__ __launch_bounds__(512, 4)
void fused_net(const float* __restrict__ x, const float2* __restrict__ tables,
               const unsigned short* __restrict__ W0, const unsigned short* __restrict__ W1,
               const unsigned short* __restrict__ W2,
               const float* __restrict__ b0, const float* __restrict__ b1, const float* __restrict__ b2,
               float* __restrict__ out, Levels lv) {
    __shared__ __align__(16) char smem[65536 + 64 * 3 * 4 + 4 * 16 * 4];
    float* xls = (float*)(smem + 65536);
    unsigned* sR  = (unsigned*)(smem + 65536 + 768);
    unsigned* sMY = sR + 16;
    unsigned* sMZ = sR + 32;
    unsigned* sDF = sR + 48;
    char* buf0 = smem;            // h0, later h2
    char* buf1 = smem + 32768;    // h1
    const int tid = threadIdx.x;
    const int blk = blockIdx.x;

    for (int i = tid; i < 64 * 3; i += 512) xls[i] = x[(size_t)blk * 64 * 3 + i];
    if (tid == 0) {
#pragma unroll
        for (int i = 0; i < 16; ++i) { sR[i] = lv.R[i]; sMY[i] = lv.mY[i]; sMZ[i] = lv.mZ[i]; sDF[i] = lv.df[i]; }
    }
    __syncthreads();

    const int p = tid >> 3, sub = tid & 7;
    const float xr0 = xls[p * 3 + 0], xr1 = xls[p * 3 + 1], xr2 = xls[p * 3 + 2];

    // ---- positional embedding: ~5 cols per sub-thread ----
    {
        int e = sub * 5 + 5; if (e > 39) e = 39;
        for (int c = sub * 5; c < e; ++c) {
            float v;
            if (c < 3) v = (c == 0) ? xr0 : (c == 1 ? xr1 : xr2);
            else {
                int q = c - 3, j = q / 6, k = q - j * 6;
                int axis = (k < 3) ? k : k - 3;
                float xv = axis == 0 ? xr0 : (axis == 1 ? xr1 : xr2);
                float fx = (float)(1 << j) * xv;
                v = (k < 3) ? __sinf(fx) : __cosf(fx);
            }
            stb(buf0, p, c, v);
        }
        for (int c = 71 + sub; c < 96; c += 8) stb(buf0, p, c, 0.f);
    }

    // ---- hash grid: 2 levels per sub-thread ----
    {
        const float cx = fminf(fmaxf(xr0, 0.f), 1.f);
        const float cy = fminf(fmaxf(xr1, 0.f), 1.f);
        const float cz = fminf(fmaxf(xr2, 0.f), 1.f);
#pragma unroll
        for (int t = 0; t < 2; ++t) {
            const int l = sub * 2 + t;
            const unsigned Ru = sR[l], mY = sMY[l], mZ = sMZ[l];
            const bool dense = sDF[l] != 0;
            const unsigned lofs = (unsigned)l << 19;
            const float Rf = (float)Ru;
            float px = cx * Rf, py = cy * Rf, pz = cz * Rf;
            float fx = floorf(px), fy = floorf(py), fz = floorf(pz);
            float wx = px - fx, wy = py - fy, wz = pz - fz;
            unsigned ix = (unsigned)fx, iy = (unsigned)fy, iz = (unsigned)fz;
            unsigned xc0 = ix, xc1 = umin_(ix + 1u, Ru);
            unsigned y0 = iy * mY, y1 = umin_(iy + 1u, Ru) * mY;
            unsigned z0 = iz * mZ, z1 = umin_(iz + 1u, Ru) * mZ;
            unsigned yzA[4] = { y0 + z0 + lofs, y1 + z0 + lofs, y0 + z1 + lofs, y1 + z1 + lofs };
            unsigned yzX[4] = { y0 ^ z0, y1 ^ z0, y0 ^ z1, y1 ^ z1 };
            float w0x = 1.f - wx, w0y = 1.f - wy, w0z = 1.f - wz;
            float wyz[4] = { w0y * w0z, wy * w0z, w0y * wz, wy * wz };
            float a0 = 0.f, a1 = 0.f;
#pragma unroll
            for (int c = 0; c < 8; ++c) {
                const int ox = c & 1, cyz = c >> 1;
                unsigned xc = ox ? xc1 : xc0;
                unsigned fd = xc + yzA[cyz];
                unsigned fh = ((xc ^ yzX[cyz]) & (T_HASH - 1u)) + lofs;
                unsigned gi = dense ? fd : fh;
                float2 e2 = tables[gi];
                float wc = (ox ? wx : w0x) * wyz[cyz];
                a0 = fmaf(wc, e2.x, a0);
                a1 = fmaf(wc, e2.y, a1);
            }
            stb(buf0, p, 39 + 2 * l, a0);
            stb(buf0, p, 40 + 2 * l, a1);
        }
    }
    __syncthreads();

    layer_lds(buf0, W0, 96, b0, buf1, tid, 3);   // 71(->96) -> 256
    __syncthreads();
    layer_lds(buf1, W1, 256, b1, buf0, tid, 8);  // 256 -> 256
    __syncthreads();
    layer_out(buf0, W2, b2, out, tid, blk);      // 256 -> 257 (padded 272)
}

extern "C" void kernel_launch(void* const* d_in, const int* in_sizes, int n_in,
                              void* d_out, int out_size, void* d_ws, size_t ws_size,
                              hipStream_t stream) {
    const float*  x      = (const float*)d_in[0];
    const float2* tables = (const float2*)d_in[1];
    const float*  v0 = (const float*)d_in[2];
    const float*  g0 = (const float*)d_in[3];
    const float*  b0 = (const float*)d_in[4];
    const float*  v1 = (const float*)d_in[5];
    const float*  g1 = (const float*)d_in[6];
    const float*  b1 = (const float*)d_in[7];
    const float*  v2 = (const float*)d_in[8];
    const float*  g2 = (const float*)d_in[9];
    const float*  b2 = (const float*)d_in[10];

    unsigned short* W0 = (unsigned short*)d_ws;          // [256][96]
    unsigned short* W1 = W0 + 256 * 96;                  // [256][256]
    unsigned short* W2 = W1 + 256 * 256;                 // [272][256]

    Levels lv;
    double SCALE = pow(2.0, log2(2048.0 / 16.0) / 15.0);
    for (int l = 0; l < 16; ++l) {
        double r = 16.0 * pow(SCALE, (double)l);
        unsigned R = (unsigned)ceil(r);
        lv.R[l] = R;
        unsigned long long s = (unsigned long long)R + 1;
        int dense = (s * s * s <= (unsigned long long)T_HASH) ? 1 : 0;
        lv.df[l] = dense;
        lv.mY[l] = dense ? (R + 1u) : PRIME1;
        lv.mZ[l] = dense ? (R + 1u) * (R + 1u) : PRIME2;
    }

    prep_weights<<<784, 64, 0, stream>>>(v0, g0, v1, g1, v2, g2, W0, W1, W2);

    int n = in_sizes[0] / 3;          // 524288
    int nblk = n / 64;                // 8192
    fused_net<<<nblk, 512, 0, stream>>>(x, tables, W0, W1, W2, b0, b1, b2, (float*)d_out, lv);
}

// Round 3
// 950.476 us; speedup vs baseline: 1.4185x; 1.0229x over previous
//
#include <hip/hip_runtime.h>
#include <math.h>

typedef __bf16 bf16;
typedef __attribute__((ext_vector_type(8))) __bf16 bf16x8;
typedef __attribute__((ext_vector_type(4))) float f32x4;

#define T_HASH (1u << 19)
#define PRIME1 2654435761u
#define PRIME2 805459861u

struct Levels { unsigned R[16]; unsigned mY[16]; unsigned mZ[16]; unsigned df[16]; };

__device__ __forceinline__ unsigned umin_(unsigned a, unsigned b) { return a < b ? a : b; }

// swizzled LDS byte offset: rows are 512B (256 bf16), XOR row-bits into the 16B-slot bits
__device__ __forceinline__ int swzoff(int row, int colByte) {
    return row * 512 + (colByte ^ ((row & 7) << 4));
}

__device__ __forceinline__ void stb(char* base, int row, int col, float v) {
    *(bf16*)(base + swzoff(row, col * 2)) = (bf16)v;
}

// fast softplus(100v)/100: v_exp/v_log based; v>0.25 -> identity (tail < 2e-13)
__device__ __forceinline__ float softplus100f(float v) {
    float u = v * 144.2695041f;                       // 100 * log2(e)
    float e = __builtin_amdgcn_exp2f(u);
    float y = __builtin_amdgcn_logf(1.f + e) * 0.006931471806f;  // log2->ln, /100
    return v > 0.25f ? v : y;
}

// ---------------- weight prep: W = g * v / ||v||_row, cast to bf16, pad ----------------
__global__ void prep_weights(const float* __restrict__ v0, const float* __restrict__ g0,
                             const float* __restrict__ v1, const float* __restrict__ g1,
                             const float* __restrict__ v2, const float* __restrict__ g2,
                             unsigned short* __restrict__ W0, unsigned short* __restrict__ W1,
                             unsigned short* __restrict__ W2) {
    int r = blockIdx.x;
    int lane = threadIdx.x;
    const float* src = nullptr; const float* g = nullptr; unsigned short* dst; int K, Kp, row;
    if (r < 256)      { row = r;       src = v0 + row * 71;  g = g0; dst = W0 + row * 96;  K = 71;  Kp = 96;  }
    else if (r < 512) { row = r - 256; src = v1 + row * 256; g = g1; dst = W1 + row * 256; K = 256; Kp = 256; }
    else              { row = r - 512; if (row < 257) { src = v2 + row * 256; g = g2; }
                        dst = W2 + row * 256; K = 256; Kp = 256; }
    float ss = 0.f;
    if (src) for (int c = lane; c < K; c += 64) { float v = src[c]; ss += v * v; }
    for (int off = 32; off; off >>= 1) ss += __shfl_down(ss, off);
    ss = __shfl(ss, 0);
    float scale = src ? (g[row] / sqrtf(ss)) : 0.f;
    for (int c = lane; c < Kp; c += 64) {
        float v = (src && c < K) ? src[c] * scale : 0.f;
        bf16 h = (bf16)v;
        dst[c] = *(unsigned short*)&h;
    }
}

// ---------------- fused: encode -> L1 -> L2 -> L3 ----------------
// block = 64 points, 1024 threads (16 waves). wave: wm = wave>>3 (2), wn = wave&7 (8)
// each wave owns a 32-row x 32-col output slice: acc[2][2] tiles, nt = wn + 8*nr

__device__ __forceinline__ void layer_lds(const char* __restrict__ inbuf,
                                          const unsigned short* __restrict__ W, const int rowlen,
                                          const float* __restrict__ bias,
                                          char* __restrict__ outbuf, int tid, int ksteps) {
    const int lane = tid & 63, wave = tid >> 6;
    const int wm = wave >> 3, wn = wave & 7;
    const int lrow = lane & 15, lk = lane >> 4;
    f32x4 acc[2][2] = {};
    for (int ks = 0; ks < ksteps; ++ks) {
        const int k0 = ks * 32 + lk * 8;
        bf16x8 a[2], b[2];
#pragma unroll
        for (int mr = 0; mr < 2; ++mr) {
            int row = wm * 32 + mr * 16 + lrow;
            a[mr] = *(const bf16x8*)(inbuf + swzoff(row, k0 * 2));
        }
#pragma unroll
        for (int nr = 0; nr < 2; ++nr) {
            int wrow = (wn + 8 * nr) * 16 + lrow;
            b[nr] = *(const bf16x8*)(W + wrow * rowlen + k0);
        }
#pragma unroll
        for (int mr = 0; mr < 2; ++mr)
#pragma unroll
            for (int nr = 0; nr < 2; ++nr)
                acc[mr][nr] = __builtin_amdgcn_mfma_f32_16x16x32_bf16(a[mr], b[nr], acc[mr][nr], 0, 0, 0);
    }
#pragma unroll
    for (int mr = 0; mr < 2; ++mr)
#pragma unroll
        for (int nr = 0; nr < 2; ++nr) {
            int col = (wn + 8 * nr) * 16 + lrow;
            float bv = bias[col];
#pragma unroll
            for (int j = 0; j < 4; ++j) {
                int row = wm * 32 + mr * 16 + lk * 4 + j;
                stb(outbuf, row, col, softplus100f(acc[mr][nr][j] + bv));
            }
        }
}

__device__ __forceinline__ void layer_out(const char* __restrict__ inbuf,
                                          const unsigned short* __restrict__ W2,
                                          const float* __restrict__ b2,
                                          float* __restrict__ out, int tid, int blk) {
    const int lane = tid & 63, wave = tid >> 6;
    const int wm = wave >> 3, wn = wave & 7;
    const int lrow = lane & 15, lk = lane >> 4;
    f32x4 acc[2][3] = {};
    for (int ks = 0; ks < 8; ++ks) {
        const int k0 = ks * 32 + lk * 8;
        bf16x8 a[2];
#pragma unroll
        for (int mr = 0; mr < 2; ++mr) {
            int row = wm * 32 + mr * 16 + lrow;
            a[mr] = *(const bf16x8*)(inbuf + swzoff(row, k0 * 2));
        }
#pragma unroll
        for (int nr = 0; nr < 3; ++nr) {
            int nt = wn + 8 * nr;
            if (nt > 16) continue;
            bf16x8 b = *(const bf16x8*)(W2 + (nt * 16 + lrow) * 256 + k0);
#pragma unroll
            for (int mr = 0; mr < 2; ++mr)
                acc[mr][nr] = __builtin_amdgcn_mfma_f32_16x16x32_bf16(a[mr], b, acc[mr][nr], 0, 0, 0);
        }
    }
#pragma unroll
    for (int nr = 0; nr < 3; ++nr) {
        int nt = wn + 8 * nr;
        if (nt > 16) continue;
        int col = nt * 16 + lrow;
        if (col >= 257) continue;
        float bv = b2[col];
#pragma unroll
        for (int mr = 0; mr < 2; ++mr)
#pragma unroll
            for (int j = 0; j < 4; ++j) {
                int row = wm * 32 + mr * 16 + lk * 4 + j;
                out[(size_t)(blk * 64 + row) * 257 + col] = acc[mr][nr][j] + bv;
            }
    }
}

__global__ __launch_bounds__(1024, 8)
void fused_net(const float* __restrict__ x, const float2* __restrict__ tables,
               const unsigned short* __restrict__ W0, const unsigned short* __restrict__ W1,
               const unsigned short* __restrict__ W2,
               const float* __restrict__ b0, const float* __restrict__ b1, const float* __restrict__ b2,
               float* __restrict__ out, Levels lv) {
    __shared__ __align__(16) char smem[65536 + 64 * 3 * 4 + 4 * 16 * 4];
    float* xls = (float*)(smem + 65536);
    unsigned* sR  = (unsigned*)(smem + 65536 + 768);
    unsigned* sMY = sR + 16;
    unsigned* sMZ = sR + 32;
    unsigned* sDF = sR + 48;
    char* buf0 = smem;            // h0, later h2
    char* buf1 = smem + 32768;    // h1
    const int tid = threadIdx.x;
    const int blk = blockIdx.x;

    if (tid < 192) xls[tid] = x[(size_t)blk * 192 + tid];
    if (tid >= 192 && tid < 256) {
        int i = tid - 192;
        sR[i & 15] = lv.R[i & 15];
        if (i < 16)      sR[i]  = lv.R[i];
        else if (i < 32) sMY[i - 16] = lv.mY[i - 16];
        else if (i < 48) sMZ[i - 32] = lv.mZ[i - 32];
        else             sDF[i - 48] = lv.df[i - 48];
    }
    __syncthreads();

    const int p = tid >> 4, sub = tid & 15;
    const float xr0 = xls[p * 3 + 0], xr1 = xls[p * 3 + 1], xr2 = xls[p * 3 + 2];

    // ---- positional embedding: 3 cols per sub-thread (subs 0..12) ----
    if (sub < 13) {
        int c0 = sub * 3;
#pragma unroll
        for (int u = 0; u < 3; ++u) {
            int c = c0 + u;
            if (c >= 39) break;
            float v;
            if (c < 3) v = (c == 0) ? xr0 : (c == 1 ? xr1 : xr2);
            else {
                int q = c - 3, j = q / 6, k = q - j * 6;
                int axis = (k < 3) ? k : k - 3;
                float xv = axis == 0 ? xr0 : (axis == 1 ? xr1 : xr2);
                float fx = (float)(1 << j) * xv;
                v = (k < 3) ? __sinf(fx) : __cosf(fx);
            }
            stb(buf0, p, c, v);
        }
    }
    for (int c = 71 + sub; c < 96; c += 16) stb(buf0, p, c, 0.f);

    // ---- hash grid: exactly 1 level per sub-thread ----
    {
        const int l = sub;
        const float cx = fminf(fmaxf(xr0, 0.f), 1.f);
        const float cy = fminf(fmaxf(xr1, 0.f), 1.f);
        const float cz = fminf(fmaxf(xr2, 0.f), 1.f);
        const unsigned Ru = sR[l], mY = sMY[l], mZ = sMZ[l];
        const bool dense = sDF[l] != 0;
        const unsigned lofs = (unsigned)l << 19;
        const float Rf = (float)Ru;
        float px = cx * Rf, py = cy * Rf, pz = cz * Rf;
        float fx = floorf(px), fy = floorf(py), fz = floorf(pz);
        float wx = px - fx, wy = py - fy, wz = pz - fz;
        unsigned ix = (unsigned)fx, iy = (unsigned)fy, iz = (unsigned)fz;
        unsigned xc0 = ix, xc1 = umin_(ix + 1u, Ru);
        unsigned y0 = iy * mY, y1 = umin_(iy + 1u, Ru) * mY;
        unsigned z0 = iz * mZ, z1 = umin_(iz + 1u, Ru) * mZ;
        unsigned yzA[4] = { y0 + z0 + lofs, y1 + z0 + lofs, y0 + z1 + lofs, y1 + z1 + lofs };
        unsigned yzX[4] = { y0 ^ z0, y1 ^ z0, y0 ^ z1, y1 ^ z1 };
        float w0x = 1.f - wx, w0y = 1.f - wy, w0z = 1.f - wz;
        float wyz[4] = { w0y * w0z, wy * w0z, w0y * wz, wy * wz };
        float a0 = 0.f, a1 = 0.f;
#pragma unroll
        for (int c = 0; c < 8; ++c) {
            const int ox = c & 1, cyz = c >> 1;
            unsigned xc = ox ? xc1 : xc0;
            unsigned fd = xc + yzA[cyz];
            unsigned fh = ((xc ^ yzX[cyz]) & (T_HASH - 1u)) + lofs;
            unsigned gi = dense ? fd : fh;
            float2 e2 = tables[gi];
            float wc = (ox ? wx : w0x) * wyz[cyz];
            a0 = fmaf(wc, e2.x, a0);
            a1 = fmaf(wc, e2.y, a1);
        }
        stb(buf0, p, 39 + 2 * l, a0);
        stb(buf0, p, 40 + 2 * l, a1);
    }
    __syncthreads();

    layer_lds(buf0, W0, 96, b0, buf1, tid, 3);   // 71(->96) -> 256
    __syncthreads();
    layer_lds(buf1, W1, 256, b1, buf0, tid, 8);  // 256 -> 256
    __syncthreads();
    layer_out(buf0, W2, b2, out, tid, blk);      // 256 -> 257 (padded 272)
}

extern "C" void kernel_launch(void* const* d_in, const int* in_sizes, int n_in,
                              void* d_out, int out_size, void* d_ws, size_t ws_size,
                              hipStream_t stream) {
    const float*  x      = (const float*)d_in[0];
    const float2* tables = (const float2*)d_in[1];
    const float*  v0 = (const float*)d_in[2];
    const float*  g0 = (const float*)d_in[3];
    const float*  b0 = (const float*)d_in[4];
    const float*  v1 = (const float*)d_in[5];
    const float*  g1 = (const float*)d_in[6];
    const float*  b1 = (const float*)d_in[7];
    const float*  v2 = (const float*)d_in[8];
    const float*  g2 = (const float*)d_in[9];
    const float*  b2 = (const float*)d_in[10];

    unsigned short* W0 = (unsigned short*)d_ws;          // [256][96]
    unsigned short* W1 = W0 + 256 * 96;                  // [256][256]
    unsigned short* W2 = W1 + 256 * 256;                 // [272][256]

    Levels lv;
    double SCALE = pow(2.0, log2(2048.0 / 16.0) / 15.0);
    for (int l = 0; l < 16; ++l) {
        double r = 16.0 * pow(SCALE, (double)l);
        unsigned R = (unsigned)ceil(r);
        lv.R[l] = R;
        unsigned long long s = (unsigned long long)R + 1;
        int dense = (s * s * s <= (unsigned long long)T_HASH) ? 1 : 0;
        lv.df[l] = dense;
        lv.mY[l] = dense ? (R + 1u) : PRIME1;
        lv.mZ[l] = dense ? (R + 1u) * (R + 1u) : PRIME2;
    }

    prep_weights<<<784, 64, 0, stream>>>(v0, g0, v1, g1, v2, g2, W0, W1, W2);

    int n = in_sizes[0] / 3;          // 524288
    int nblk = n / 64;                // 8192
    fused_net<<<nblk, 1024, 0, stream>>>(x, tables, W0, W1, W2, b0, b1, b2, (float*)d_out, lv);
}